// Round 1
// baseline (564.339 us; speedup 1.0000x reference)
//
#include <hip/hip_runtime.h>

// out[row, :] = 1 / where(d[idx,:]==0, BIG, d[idx,:])
// idx = venueid2coor[inputs_poi[row]], row in [0, B*S)
// N_POI = 10000 -> 2500 float4 per row, 40000-byte row stride (16B aligned).
//
// Restructured for memory-level parallelism: the row is processed as
// 10 uniform chunks of 250 float4. All 10 loads are issued back-to-back
// (independent global_load_dwordx4, no interleaved stores sharing vmcnt),
// then the select+divide+store runs as the loads drain. The previous
// version's load->div->store loop kept ~1 load in flight per wave because
// loads and stores share vmcnt on CDNA.

typedef float v4f __attribute__((ext_vector_type(4)));

#define ROW_F4 2500
#define CHUNK  250          // active lanes per chunk; 10 * 250 == 2500
#define NCHUNK 10
#define BIGF   9999999.99f  // rounds to 1e7f in fp32, matching the jnp.float32 ref

__global__ __launch_bounds__(256) void attn_loc_distance_kernel(
    const int* __restrict__ v2c,        // [V] venue id -> matrix row
    const int* __restrict__ poi,        // [B*S] venue ids
    const v4f* __restrict__ dmat,       // [N_POI, ROW_F4]
    v4f* __restrict__ out) {            // [B*S, ROW_F4]
    const int row = blockIdx.x;
    // wave-uniform double indirection (scalar loads, broadcast to all lanes)
    const int idx = v2c[poi[row]];
    const v4f* __restrict__ src = dmat + (size_t)idx * ROW_F4;
    v4f* __restrict__ dst = out + (size_t)row * ROW_F4;

    const int t = threadIdx.x;
    if (t >= CHUNK) return;             // 6 idle lanes in wave 3 only

    // Phase 1: issue all loads. Independent addresses -> 10 loads in flight
    // per thread, 2.5 KB/lane, ~40 KB per block outstanding.
    v4f x[NCHUNK];
#pragma unroll
    for (int k = 0; k < NCHUNK; ++k)
        x[k] = src[k * CHUNK + t];

    // Phase 2: mask zeros, reciprocal, stream out. Nontemporal: the 256 MiB
    // write-once stream must not evict the gathered distance rows (~1.35x
    // read reuse) from L2/L3.
#pragma unroll
    for (int k = 0; k < NCHUNK; ++k) {
        v4f y;
        y.x = 1.0f / ((x[k].x == 0.0f) ? BIGF : x[k].x);
        y.y = 1.0f / ((x[k].y == 0.0f) ? BIGF : x[k].y);
        y.z = 1.0f / ((x[k].z == 0.0f) ? BIGF : x[k].z);
        y.w = 1.0f / ((x[k].w == 0.0f) ? BIGF : x[k].w);
        __builtin_nontemporal_store(y, dst + k * CHUNK + t);
    }
}

extern "C" void kernel_launch(void* const* d_in, const int* in_sizes, int n_in,
                              void* d_out, int out_size, void* d_ws, size_t ws_size,
                              hipStream_t stream) {
    const int*   v2c  = (const int*)d_in[0];     // venueid2coor (int32 on device)
    const int*   poi  = (const int*)d_in[1];     // inputs_poi   (int32 on device)
    const float* dmat = (const float*)d_in[2];   // poi_distance_matrix
    float*       out  = (float*)d_out;

    const int rows = in_sizes[1];                // B*S = 6400
    attn_loc_distance_kernel<<<rows, 256, 0, stream>>>(
        v2c, poi, (const v4f*)dmat, (v4f*)out);
}

// Round 2
// 560.554 us; speedup vs baseline: 1.0068x; 1.0068x over previous
//
#include <hip/hip_runtime.h>

// out[row, :] = 1 / where(d[idx,:]==0, BIG, d[idx,:])
// idx = venueid2coor[inputs_poi[row]], row in [0, B*S)
// N_POI = 10000 -> 2500 float4 per row, 40000-byte row stride (16B aligned).
//
// Round-2 probe: 2 blocks per row (12800 blocks, half-row = 1250 float4 each,
// 5 chunks of 250). Discriminates latency-limited (helps) vs BW-bound
// (neutral). Keeps the phase-split load structure: all 5 loads issued
// back-to-back before any store shares vmcnt.

typedef float v4f __attribute__((ext_vector_type(4)));

#define ROW_F4   2500
#define HALF_F4  1250
#define CHUNK    250          // active lanes per chunk; 5 * 250 == 1250
#define NCHUNK   5
#define BIGF     9999999.99f  // rounds to 1e7f in fp32, matching the jnp.float32 ref

__global__ __launch_bounds__(256) void attn_loc_distance_kernel(
    const int* __restrict__ v2c,        // [V] venue id -> matrix row
    const int* __restrict__ poi,        // [B*S] venue ids
    const v4f* __restrict__ dmat,       // [N_POI, ROW_F4]
    v4f* __restrict__ out) {            // [B*S, ROW_F4]
    const int row  = blockIdx.x >> 1;
    const int half = blockIdx.x & 1;
    // wave-uniform double indirection (scalar loads, broadcast to all lanes)
    const int idx = v2c[poi[row]];
    const v4f* __restrict__ src = dmat + (size_t)idx * ROW_F4 + half * HALF_F4;
    v4f* __restrict__ dst = out + (size_t)row * ROW_F4 + half * HALF_F4;

    const int t = threadIdx.x;
    if (t >= CHUNK) return;             // 6 idle lanes in wave 3 only

    // Phase 1: issue all loads back-to-back (independent global_load_dwordx4,
    // no interleaved stores sharing vmcnt).
    v4f x[NCHUNK];
#pragma unroll
    for (int k = 0; k < NCHUNK; ++k)
        x[k] = src[k * CHUNK + t];

    // Phase 2: mask zeros, reciprocal, stream out. Nontemporal: the 256 MiB
    // write-once stream must not evict the gathered distance rows (~1.35x
    // read reuse) from L2/L3.
#pragma unroll
    for (int k = 0; k < NCHUNK; ++k) {
        v4f y;
        y.x = 1.0f / ((x[k].x == 0.0f) ? BIGF : x[k].x);
        y.y = 1.0f / ((x[k].y == 0.0f) ? BIGF : x[k].y);
        y.z = 1.0f / ((x[k].z == 0.0f) ? BIGF : x[k].z);
        y.w = 1.0f / ((x[k].w == 0.0f) ? BIGF : x[k].w);
        __builtin_nontemporal_store(y, dst + k * CHUNK + t);
    }
}

extern "C" void kernel_launch(void* const* d_in, const int* in_sizes, int n_in,
                              void* d_out, int out_size, void* d_ws, size_t ws_size,
                              hipStream_t stream) {
    const int*   v2c  = (const int*)d_in[0];     // venueid2coor (int32 on device)
    const int*   poi  = (const int*)d_in[1];     // inputs_poi   (int32 on device)
    const float* dmat = (const float*)d_in[2];   // poi_distance_matrix
    float*       out  = (float*)d_out;

    const int rows = in_sizes[1];                // B*S = 6400
    attn_loc_distance_kernel<<<rows * 2, 256, 0, stream>>>(
        v2c, poi, (const v4f*)dmat, (v4f*)out);
}

// Round 3
// 559.036 us; speedup vs baseline: 1.0095x; 1.0027x over previous
//
#include <hip/hip_runtime.h>

// out[row, :] = 1 / where(d[idx,:]==0, BIG, d[idx,:])
// idx = venueid2coor[inputs_poi[row]], row in [0, B*S)
// N_POI = 10000 -> 2500 float4 per row, 40000-byte row stride (16B aligned).
//
// Round-3 A/B probe: identical to round 2 EXCEPT nontemporal store -> plain
// vector store. The harness fill kernel reaches 6.4 TB/s with plain stores;
// if our kernel was NT-store-throttled this recovers ~3x. If dur_us is
// unchanged, the kernel is at the memory roofline (~60-70 us) and the
// iteration floor (~500 us) is harness poison fills.

typedef float v4f __attribute__((ext_vector_type(4)));

#define ROW_F4   2500
#define HALF_F4  1250
#define CHUNK    250          // active lanes per chunk; 5 * 250 == 1250
#define NCHUNK   5
#define BIGF     9999999.99f  // rounds to 1e7f in fp32, matching the jnp.float32 ref

__global__ __launch_bounds__(256) void attn_loc_distance_kernel(
    const int* __restrict__ v2c,        // [V] venue id -> matrix row
    const int* __restrict__ poi,        // [B*S] venue ids
    const v4f* __restrict__ dmat,       // [N_POI, ROW_F4]
    v4f* __restrict__ out) {            // [B*S, ROW_F4]
    const int row  = blockIdx.x >> 1;
    const int half = blockIdx.x & 1;
    // wave-uniform double indirection (scalar loads, broadcast to all lanes)
    const int idx = v2c[poi[row]];
    const v4f* __restrict__ src = dmat + (size_t)idx * ROW_F4 + half * HALF_F4;
    v4f* __restrict__ dst = out + (size_t)row * ROW_F4 + half * HALF_F4;

    const int t = threadIdx.x;
    if (t >= CHUNK) return;             // 6 idle lanes in wave 3 only

    // Phase 1: issue all loads back-to-back (independent global_load_dwordx4,
    // no interleaved stores sharing vmcnt).
    v4f x[NCHUNK];
#pragma unroll
    for (int k = 0; k < NCHUNK; ++k)
        x[k] = src[k * CHUNK + t];

    // Phase 2: mask zeros, reciprocal, plain streaming store.
#pragma unroll
    for (int k = 0; k < NCHUNK; ++k) {
        v4f y;
        y.x = 1.0f / ((x[k].x == 0.0f) ? BIGF : x[k].x);
        y.y = 1.0f / ((x[k].y == 0.0f) ? BIGF : x[k].y);
        y.z = 1.0f / ((x[k].z == 0.0f) ? BIGF : x[k].z);
        y.w = 1.0f / ((x[k].w == 0.0f) ? BIGF : x[k].w);
        dst[k * CHUNK + t] = y;
    }
}

extern "C" void kernel_launch(void* const* d_in, const int* in_sizes, int n_in,
                              void* d_out, int out_size, void* d_ws, size_t ws_size,
                              hipStream_t stream) {
    const int*   v2c  = (const int*)d_in[0];     // venueid2coor (int32 on device)
    const int*   poi  = (const int*)d_in[1];     // inputs_poi   (int32 on device)
    const float* dmat = (const float*)d_in[2];   // poi_distance_matrix
    float*       out  = (float*)d_out;

    const int rows = in_sizes[1];                // B*S = 6400
    attn_loc_distance_kernel<<<rows * 2, 256, 0, stream>>>(
        v2c, poi, (const v4f*)dmat, (v4f*)out);
}